// Round 3
// baseline (334.256 us; speedup 1.0000x reference)
//
#include <hip/hip_runtime.h>
#include <stdint.h>

#define LOG2E 1.4426950408889634f

typedef __attribute__((ext_vector_type(8))) short short8;
typedef __attribute__((ext_vector_type(4))) float floatx4;
typedef unsigned int u32;

__device__ __forceinline__ float bf2f(unsigned short h) {
  union { unsigned int u; float f; } v; v.u = ((unsigned int)h) << 16; return v.f;
}
__device__ __forceinline__ unsigned short f2bf(float f) {
  union { float f; unsigned int u; } v; v.f = f;
  unsigned int r = v.u + 0x7FFFu + ((v.u >> 16) & 1u);
  return (unsigned short)(r >> 16);
}
__device__ __forceinline__ u32 fbits(float f) {
  union { float f; u32 u; } v; v.f = f; return v.u;
}
// async global->LDS, 16B per lane. dst must be wave-contiguous (base + lane*16).
__device__ __forceinline__ void async16(void* lds, const void* g) {
  __builtin_amdgcn_global_load_lds((const __attribute__((address_space(1))) u32*)g,
                                   (__attribute__((address_space(3))) u32*)lds, 16, 0, 0);
}

// ---------------------------------------------------------------------------
// fp32 -> bf16 elementwise convert (8 elems/thread, vectorized)
__global__ __launch_bounds__(256) void cvt_f32_bf16(const float* __restrict__ src,
                                                    unsigned short* __restrict__ dst, int n) {
  int i = (blockIdx.x * 256 + threadIdx.x) * 8;
  if (i >= n) return;
  float4 a = ((const float4*)(src + i))[0];
  float4 b = ((const float4*)(src + i))[1];
  union { uint4 v; unsigned short u[8]; } o;
  o.u[0] = f2bf(a.x); o.u[1] = f2bf(a.y); o.u[2] = f2bf(a.z); o.u[3] = f2bf(a.w);
  o.u[4] = f2bf(b.x); o.u[5] = f2bf(b.y); o.u[6] = f2bf(b.z); o.u[7] = f2bf(b.w);
  *(uint4*)(dst + i) = o.v;
}

// ---------------------------------------------------------------------------
// All 4 weight transposes (+fp32->bf16) in one launch. 64x64 tiles.
// blocks [0,1024): Wq->WTqkv ; [1024,1280): Wk ; [1280,1536): Wv ; [1536,2560): Wo->WoT
__global__ __launch_bounds__(256) void transpose_cvt4(const float* __restrict__ Wq,
                                                      const float* __restrict__ Wk,
                                                      const float* __restrict__ Wv,
                                                      const float* __restrict__ Wo,
                                                      unsigned short* __restrict__ WTqkv,
                                                      unsigned short* __restrict__ WoT) {
  const int R = 2048;
  int bid = blockIdx.x;
  const float* src; unsigned short* dst; int C;
  if (bid < 1024) { src = Wq; dst = WTqkv; C = 2048; }
  else if (bid < 1280) { src = Wk; dst = WTqkv + (size_t)2048 * 2048; C = 512; bid -= 1024; }
  else if (bid < 1536) { src = Wv; dst = WTqkv + (size_t)2048 * 2048 + (size_t)512 * 2048; C = 512; bid -= 1280; }
  else { src = Wo; dst = WoT; C = 2048; bid -= 1536; }

  __shared__ unsigned short tile[64][65];
  int tc = C >> 6;
  int br = bid / tc, bc = bid % tc;
  int r0 = br << 6, c0 = bc << 6;
  int i = threadIdx.x >> 2, cc = (threadIdx.x & 3) << 4;
  const float4* g = (const float4*)(src + (size_t)(r0 + i) * C + c0 + cc);
  float4 f0 = g[0], f1 = g[1], f2 = g[2], f3 = g[3];
  unsigned short u[16];
  u[0]=f2bf(f0.x); u[1]=f2bf(f0.y); u[2]=f2bf(f0.z); u[3]=f2bf(f0.w);
  u[4]=f2bf(f1.x); u[5]=f2bf(f1.y); u[6]=f2bf(f1.z); u[7]=f2bf(f1.w);
  u[8]=f2bf(f2.x); u[9]=f2bf(f2.y); u[10]=f2bf(f2.z); u[11]=f2bf(f2.w);
  u[12]=f2bf(f3.x); u[13]=f2bf(f3.y); u[14]=f2bf(f3.z); u[15]=f2bf(f3.w);
#pragma unroll
  for (int j = 0; j < 16; ++j) tile[i][cc + j] = u[j];
  __syncthreads();
  union { uint4 v[2]; unsigned short u[16]; } buf;
#pragma unroll
  for (int j = 0; j < 16; ++j) buf.u[j] = tile[cc + j][i];
  uint4* o = (uint4*)(dst + (size_t)(c0 + i) * R + r0 + cc);
  o[0] = buf.v[0]; o[1] = buf.v[1];
}

// ---------------------------------------------------------------------------
// 8-phase 256x256 NT GEMM, faithful m201 structure (plain HIP).
// 512 threads = 8 waves (2M x 4N), per-wave 128x64 output, BK=64.
// LDS per matrix: [2 buf][256 rows][64 k] bf16, staged in ROW-halves (128 rows
// = 16KB = 2 x global_load_lds(16B)/thread). Chunk-XOR swizzle c^(row&7):
// conflict-floor for both linear DMA writes and quad-strided ds_read_b128.
// Phase reads 12/8/4/0 (all fragments held in regs, 24 reads/tile). Stage
// mapping: ph1 B(t+1)h0, ph2 B(t+1)h1, ph3 A(t+2)h0, ph4 A(t+2)h1 — each
// stage lands after its region's last reader passed a barrier. One counted
// vmcnt(4) per K-tile (2 half-tiles in flight); vmcnt(0) only in tail drain.
// No sched_barrier (reads are compiler-visible; pinning = m141's regression).
// Requires M%256==0, N%256==0, K%128==0, grid%8==0.
// In-session A/B (R1 vs R2): this schedule beat the k-half/sched_barrier
// variant by ~15 us and the old 128^2 structure by ~10 us on qkv.
template <typename OutT>
__global__ __launch_bounds__(512, 2) void gemm_nt_256(const unsigned short* __restrict__ A,
                                                      const unsigned short* __restrict__ BT,
                                                      OutT* __restrict__ C,
                                                      int M, int N, int K) {
  (void)M;
  __shared__ unsigned short As[2][256 * 64];
  __shared__ unsigned short Bs[2][256 * 64];
  const int nbn = N >> 8;
  const int nwg = gridDim.x;
  int wg = blockIdx.x;
  {  // XCD-aware swizzle (bijective: nwg % 8 == 0)
    int cpx = nwg >> 3;
    wg = (wg & 7) * cpx + (wg >> 3);
  }
  const int m0 = (wg / nbn) << 8;
  const int n0 = (wg % nbn) << 8;
  const int tid = threadIdx.x;
  const int lane = tid & 63, wave = tid >> 6;
  const int l15 = lane & 15, quad = lane >> 4;
  const int wr = wave >> 2, wc = wave & 3;   // 2 x 4 wave grid
  const int rA = wr * 128 + l15;             // + mf*16
  const int rB = wc * 64 + l15;              // + nf*16

  floatx4 acc[8][4];
#pragma unroll
  for (int i = 0; i < 8; ++i)
#pragma unroll
    for (int j = 0; j < 4; ++j) acc[i][j] = (floatx4){0.f, 0.f, 0.f, 0.f};

  const unsigned short* Ag = A + (size_t)m0 * K;
  const unsigned short* Bg = BT + (size_t)n0 * K;

  // Stage row-half h (rows h*128..h*128+127, full BK=64): 2 loads/thread.
  // LDS dest linear (dst + idx*16B); global source chunk pre-swizzled.
  auto STAGE = [&](unsigned short* dst, const unsigned short* g, int h) {
#pragma unroll
    for (int j = 0; j < 2; ++j) {
      int idx = j * 512 + tid;              // [0,1024)
      int row = h * 128 + (idx >> 3);
      int cl = (idx & 7) ^ (row & 7);       // logical chunk for stored chunk idx&7
      async16(dst + (size_t)h * 8192 + (size_t)idx * 8, g + (size_t)row * K + cl * 8);
    }
  };
  // read one 16B fragment at (row, ks): stored chunk = (ks*4+quad) ^ (row&7)
  auto RD = [&](const unsigned short* buf, int row, int ks) -> short8 {
    int sc = ((ks << 2) + quad) ^ (row & 7);
    return *(const short8*)(buf + row * 64 + sc * 8);
  };

#define BAR() __builtin_amdgcn_s_barrier()
#define WAITL0() asm volatile("s_waitcnt lgkmcnt(0)" ::: "memory")

  // prologue: A(0) h0,h1; B(0) h0,h1; A(1) h0,h1 = 12 loads/thread
  STAGE(As[0], Ag, 0); STAGE(As[0], Ag, 1);
  STAGE(Bs[0], Bg, 0); STAGE(Bs[0], Bg, 1);
  STAGE(As[1], Ag + 64, 0); STAGE(As[1], Ag + 64, 1);
  asm volatile("s_waitcnt vmcnt(4)" ::: "memory");   // tile0 landed; A(1) in flight
  BAR();

  const int NT = K >> 6;
  short8 a0[4][2], a1[4][2], b0[2][2], b1[2][2];
  for (int t = 0; t < NT; ++t) {
    const unsigned short* Ac = As[t & 1];
    const unsigned short* Bc = Bs[t & 1];
    unsigned short* Ast = As[t & 1];         // stage target: A(t+2)
    unsigned short* Bst = Bs[(t + 1) & 1];   // stage target: B(t+1)

    // ---- phase 1: read a0 (mf0-3) + b0 (nf0-1) [12]; stage B(t+1)h0
#pragma unroll
    for (int mf = 0; mf < 4; ++mf)
#pragma unroll
      for (int ks = 0; ks < 2; ++ks) a0[mf][ks] = RD(Ac, rA + mf * 16, ks);
#pragma unroll
    for (int nf = 0; nf < 2; ++nf)
#pragma unroll
      for (int ks = 0; ks < 2; ++ks) b0[nf][ks] = RD(Bc, rB + nf * 16, ks);
    if (t + 1 < NT) STAGE(Bst, Bg + (size_t)(t + 1) * 64, 0);
    asm volatile("s_waitcnt lgkmcnt(8)" ::: "memory");
    BAR(); WAITL0();
    __builtin_amdgcn_s_setprio(1);
#pragma unroll
    for (int mf = 0; mf < 4; ++mf)
#pragma unroll
      for (int nf = 0; nf < 2; ++nf)
#pragma unroll
        for (int ks = 0; ks < 2; ++ks)
          acc[mf][nf] = __builtin_amdgcn_mfma_f32_16x16x32_bf16(a0[mf][ks], b0[nf][ks], acc[mf][nf], 0, 0, 0);
    __builtin_amdgcn_s_setprio(0);
    BAR();

    // ---- phase 2: read a1 (mf4-7) [8]; stage B(t+1)h1
#pragma unroll
    for (int mf = 0; mf < 4; ++mf)
#pragma unroll
      for (int ks = 0; ks < 2; ++ks) a1[mf][ks] = RD(Ac, rA + 64 + mf * 16, ks);
    if (t + 1 < NT) STAGE(Bst, Bg + (size_t)(t + 1) * 64, 1);
    BAR(); WAITL0();
    __builtin_amdgcn_s_setprio(1);
#pragma unroll
    for (int mf = 0; mf < 4; ++mf)
#pragma unroll
      for (int nf = 0; nf < 2; ++nf)
#pragma unroll
        for (int ks = 0; ks < 2; ++ks)
          acc[4 + mf][nf] = __builtin_amdgcn_mfma_f32_16x16x32_bf16(a1[mf][ks], b0[nf][ks], acc[4 + mf][nf], 0, 0, 0);
    __builtin_amdgcn_s_setprio(0);
    BAR();

    // ---- phase 3: read b1 (nf2-3) [4]; stage A(t+2)h0 (A(t) dead after ph2)
#pragma unroll
    for (int nf = 0; nf < 2; ++nf)
#pragma unroll
      for (int ks = 0; ks < 2; ++ks) b1[nf][ks] = RD(Bc, rB + 32 + nf * 16, ks);
    if (t + 2 < NT) STAGE(Ast, Ag + (size_t)(t + 2) * 64, 0);
    BAR(); WAITL0();
    __builtin_amdgcn_s_setprio(1);
#pragma unroll
    for (int mf = 0; mf < 4; ++mf)
#pragma unroll
      for (int nf = 0; nf < 2; ++nf)
#pragma unroll
        for (int ks = 0; ks < 2; ++ks)
          acc[4 + mf][2 + nf] = __builtin_amdgcn_mfma_f32_16x16x32_bf16(a1[mf][ks], b1[nf][ks], acc[4 + mf][2 + nf], 0, 0, 0);
    __builtin_amdgcn_s_setprio(0);
    BAR();

    // ---- phase 4: no reads; stage A(t+2)h1; counted vmcnt(4) per tile
    if (t + 2 < NT) {
      STAGE(Ast, Ag + (size_t)(t + 2) * 64, 1);
      asm volatile("s_waitcnt vmcnt(4)" ::: "memory");  // tile t+1 fully landed
    } else {
      asm volatile("s_waitcnt vmcnt(0)" ::: "memory");  // tail drain
    }
    BAR();
    __builtin_amdgcn_s_setprio(1);
#pragma unroll
    for (int mf = 0; mf < 4; ++mf)
#pragma unroll
      for (int nf = 0; nf < 2; ++nf)
#pragma unroll
        for (int ks = 0; ks < 2; ++ks)
          acc[mf][2 + nf] = __builtin_amdgcn_mfma_f32_16x16x32_bf16(a0[mf][ks], b1[nf][ks], acc[mf][2 + nf], 0, 0, 0);
    __builtin_amdgcn_s_setprio(0);
    BAR();
  }
#undef BAR
#undef WAITL0

#pragma unroll
  for (int mf = 0; mf < 8; ++mf)
#pragma unroll
    for (int nf = 0; nf < 4; ++nf)
#pragma unroll
      for (int r = 0; r < 4; ++r) {
        int m = m0 + wr * 128 + mf * 16 + quad * 4 + r;
        int n = n0 + wc * 64 + nf * 16 + l15;
        float v = acc[mf][nf][r];
        if constexpr (sizeof(OutT) == 2)
          C[(size_t)m * N + n] = (OutT)f2bf(v);
        else
          C[(size_t)m * N + n] = (OutT)v;
      }
}

// ---------------------------------------------------------------------------
// RMS-norm + RoPE for q (heads 0..15) and k (kv 0..3).
// q gets 1/sqrt(128)*LOG2E folded in: flash then uses exp2(score) directly.
__global__ __launch_bounds__(256) void norm_rope(const unsigned short* __restrict__ qkv,
                                                 const float* __restrict__ qw,
                                                 const float* __restrict__ kw,
                                                 unsigned short* __restrict__ qT,
                                                 unsigned short* __restrict__ kT) {
  const int S = 2048;
  int wid = blockIdx.x * 4 + (threadIdx.x >> 6);
  int lane = threadIdx.x & 63;
  int slot = wid % 20;
  int bs = wid / 20;
  int s = bs & (S - 1), b = bs >> 11;
  const unsigned short* src;
  unsigned short* dst;
  const float* w;
  float scale;
  if (slot < 16) {
    src = qkv + (size_t)bs * 3072 + slot * 128;
    dst = qT + ((size_t)(b * 16 + slot) * S + s) * 128;
    w = qw; scale = 0.08838834764831845f * 1.4426950408889634f;  // 1/sqrt(128) * log2(e)
  } else {
    int kvi = slot - 16;
    src = qkv + (size_t)bs * 3072 + 2048 + kvi * 128;
    dst = kT + ((size_t)(b * 4 + kvi) * S + s) * 128;
    w = kw; scale = 1.0f;
  }
  float x1 = bf2f(src[lane]), x2 = bf2f(src[lane + 64]);
  float ss = x1 * x1 + x2 * x2;
#pragma unroll
  for (int m = 1; m < 64; m <<= 1) ss += __shfl_xor(ss, m, 64);
  float rms = rsqrtf(ss * (1.0f / 128.0f) + 1e-6f);
  float y1 = x1 * rms * w[lane];
  float y2 = x2 * rms * w[lane + 64];
  float ang = (float)s * exp2f((float)lane * -0.2076205059304601f);
  float c = cosf(ang), sn = sinf(ang);
  float o1 = (y1 * c - y2 * sn) * scale;
  float o2 = (y2 * c + y1 * sn) * scale;
  dst[lane] = f2bf(o1);
  dst[lane + 64] = f2bf(o2);
}

// ---------------------------------------------------------------------------
// V transpose: qkv v-slice (B,S,KV,128) bf16 -> vT (B,KV,128,S) bf16. 64x64 tiles.
__global__ __launch_bounds__(256) void v_transpose(const unsigned short* __restrict__ qkv,
                                                   unsigned short* __restrict__ vT) {
  const int S = 2048;
  int bid = blockIdx.x;
  int dt = bid & 1, st = (bid >> 1) & 31, kv = (bid >> 6) & 3, b = bid >> 8;
  int s0 = st << 6, d0 = dt << 6;
  __shared__ unsigned short tile[64][65];
  int i = threadIdx.x >> 2, cc = (threadIdx.x & 3) << 4;
  union { uint4 v[2]; unsigned short u[16]; } buf;
  const uint4* g = (const uint4*)(qkv + ((size_t)(b * S) + s0 + i) * 3072 + 2560 + kv * 128 + d0 + cc);
  buf.v[0] = g[0]; buf.v[1] = g[1];
#pragma unroll
  for (int j = 0; j < 16; ++j) tile[i][cc + j] = buf.u[j];
  __syncthreads();
#pragma unroll
  for (int j = 0; j < 16; ++j) buf.u[j] = tile[cc + j][i];
  uint4* o = (uint4*)(vT + ((size_t)(b * 4 + kv) * 128 + d0 + i) * S + s0 + cc);
  o[0] = buf.v[0]; o[1] = buf.v[1];
}

// ---------------------------------------------------------------------------
// MFMA flash attention v3, non-causal. Block = (b,h,128 q-rows), 4 waves x 32 rows.
// No-max softmax (scores bounded: |s|<=sqrt(128), LOG2E pre-folded into q).
// K/V double-buffered via global_load_lds prefetch; single barrier per kt.
// T5: setprio(1) around both MFMA clusters (m191 regime; R1 +4.6%).
// Byte-identical since R1 — third measurement pins the cross-run noise band
// (R0 87.7 / R1 83.7 / R2 90.0 us) before the T15/256-row restructure.
__global__ __launch_bounds__(256, 2) void flash_attn(const unsigned short* __restrict__ qT,
                                                     const unsigned short* __restrict__ kT,
                                                     const unsigned short* __restrict__ vT,
                                                     unsigned short* __restrict__ ao) {
  const int S = 2048;
  int bid = blockIdx.x;
  int qt = bid & 15, h = (bid >> 4) & 15, b = bid >> 8;
  int kv = h >> 2;
  int tid = threadIdx.x;
  int lane = tid & 63, wave = tid >> 6;
  int l15 = lane & 15, quad = lane >> 4;

  __shared__ unsigned short Ks[2][64 * 128];   // keys x dh, 16 chunks/row, XOR swizzled
  __shared__ unsigned short VTs[2][128 * 64];  // d x keys, 8 chunks/row, XOR swizzled
  __shared__ unsigned short Ps[4][32 * 64];    // per-wave P in PV-A layout, swizzled
  unsigned short* Psw = Ps[wave];

  // Q fragments (B-operand of S^T: B[n=qrow][k=dh]), register-resident
  short8 bq[2][4];
  const unsigned short* qbase = qT + ((size_t)(b * 16 + h) * S + qt * 128 + wave * 32) * 128;
#pragma unroll
  for (int nt = 0; nt < 2; ++nt)
#pragma unroll
    for (int kk = 0; kk < 4; ++kk)
      bq[nt][kk] = *(const short8*)(qbase + (size_t)(nt * 16 + l15) * 128 + kk * 32 + quad * 8);

  floatx4 O[2][8];
#pragma unroll
  for (int mt = 0; mt < 2; ++mt)
#pragma unroll
    for (int dt = 0; dt < 8; ++dt) O[mt][dt] = (floatx4){0.f, 0.f, 0.f, 0.f};
  float l_acc[2] = {0.f, 0.f};

  const size_t kbase = (size_t)(b * 4 + kv) * S * 128;
  const size_t vbase = (size_t)(b * 4 + kv) * 128 * S;

  // prefetch tile 0 into buffer 0
#pragma unroll
  for (int i = 0; i < 4; ++i) {
    int Lc = (wave * 4 + i) * 64 + lane;
    int row = Lc >> 4, cjk = (lane & 15) ^ (row & 7);
    async16(Ks[0] + (size_t)Lc * 8, kT + kbase + (size_t)row * 128 + cjk * 8);
    int d = Lc >> 3, cjv = (lane & 7) ^ (d & 7);
    async16(VTs[0] + (size_t)Lc * 8, vT + vbase + (size_t)d * S + cjv * 8);
  }

  for (int kt = 0; kt < 32; ++kt) {
    int cur = kt & 1;
    __syncthreads();  // drains prefetch for tile kt; fences reads of buf cur^1 (kt-1)
    if (kt + 1 < 32) {
#pragma unroll
      for (int i = 0; i < 4; ++i) {
        int Lc = (wave * 4 + i) * 64 + lane;
        int row = Lc >> 4, cjk = (lane & 15) ^ (row & 7);
        async16(Ks[cur ^ 1] + (size_t)Lc * 8,
                kT + kbase + (size_t)((kt + 1) * 64 + row) * 128 + cjk * 8);
        int d = Lc >> 3, cjv = (lane & 7) ^ (d & 7);
        async16(VTs[cur ^ 1] + (size_t)Lc * 8,
                vT + vbase + (size_t)d * S + (kt + 1) * 64 + cjv * 8);
      }
    }

    // S^T = K * Q^T : C[m=key][n=qrow]
    floatx4 st[4][2];
#pragma unroll
    for (int a = 0; a < 4; ++a)
#pragma unroll
      for (int nt = 0; nt < 2; ++nt) st[a][nt] = (floatx4){0.f, 0.f, 0.f, 0.f};
    __builtin_amdgcn_s_setprio(1);
#pragma unroll
    for (int kk = 0; kk < 4; ++kk)
#pragma unroll
      for (int a = 0; a < 4; ++a) {
        int m = a * 16 + l15;
        short8 ak = *(const short8*)(&Ks[cur][(m * 16 + ((kk * 4 + quad) ^ (m & 7))) * 8]);
#pragma unroll
        for (int nt = 0; nt < 2; ++nt)
          st[a][nt] = __builtin_amdgcn_mfma_f32_16x16x32_bf16(ak, bq[nt][kk], st[a][nt], 0, 0, 0);
      }
    __builtin_amdgcn_s_setprio(0);

    // P = exp2(S^T); pack to bf16 into per-wave Ps (PV-A layout); l partials per lane.
#pragma unroll
    for (int nt = 0; nt < 2; ++nt) {
      int m = nt * 16 + l15;
#pragma unroll
      for (int a = 0; a < 4; ++a) {
        float e0 = __builtin_amdgcn_exp2f(st[a][nt][0]);
        float e1 = __builtin_amdgcn_exp2f(st[a][nt][1]);
        float e2 = __builtin_amdgcn_exp2f(st[a][nt][2]);
        float e3 = __builtin_amdgcn_exp2f(st[a][nt][3]);
        l_acc[nt] += (e0 + e1) + (e2 + e3);
        u32 p01 = __builtin_amdgcn_perm(fbits(e1) + 0x8000u, fbits(e0) + 0x8000u, 0x07060302u);
        u32 p23 = __builtin_amdgcn_perm(fbits(e3) + 0x8000u, fbits(e2) + 0x8000u, 0x07060302u);
        int c = (a * 2 + (quad >> 1)) ^ (m & 7);
        uint2 pk; pk.x = p01; pk.y = p23;
        *(uint2*)(&Psw[(m * 8 + c) * 8 + (quad & 1) * 4]) = pk;
      }
    }

    // PV: O[m=qrow][n=d] += P[m][key] * VT[n][key]
    __builtin_amdgcn_s_setprio(1);
#pragma unroll
    for (int kk2 = 0; kk2 < 2; ++kk2) {
      short8 ap[2];
#pragma unroll
      for (int mt = 0; mt < 2; ++mt) {
        int m = mt * 16 + l15;
        ap[mt] = *(const short8*)(&Psw[(m * 8 + ((kk2 * 4 + quad) ^ (m & 7))) * 8]);
      }
#pragma unroll
      for (int dt = 0; dt < 8; ++dt) {
        int n = dt * 16 + l15;
        short8 bv = *(const short8*)(&VTs[cur][(n * 8 + ((kk2 * 4 + quad) ^ (n & 7))) * 8]);
#pragma unroll
        for (int mt = 0; mt < 2; ++mt)
          O[mt][dt] = __builtin_amdgcn_mfma_f32_16x16x32_bf16(ap[mt], bv, O[mt][dt], 0, 0, 0);
      }
    }
    __builtin_amdgcn_s_setprio(0);
  }

  // epilogue: reduce l across quads, normalize, store
  float linv[2];
#pragma unroll
  for (int nt = 0; nt < 2; ++nt) {
    float l = l_acc[nt];
    l += __shfl_xor(l, 16, 64);
    l += __shfl_xor(l, 32, 64);
    linv[nt] = 1.f / l;
  }
#pragma unroll
  for (int mt = 0; mt < 2; ++mt)
#pragma unroll
    for (int r = 0; r < 4; ++r) {
      float inv = __shfl(linv[mt], quad * 4 + r, 64);
      int s = qt * 128 + wave * 32 + mt * 16 + quad * 4 + r;
#pragma unroll
      for (int dt = 0; dt < 8; ++dt) {
        int d = dt * 16 + l15;
        ao[((size_t)(b * S + s) * 16 + h) * 128 + d] = f2bf(O[mt][dt][r] * inv);
      }
    }
}

// ---------------------------------------------------------------------------
extern "C" void kernel_launch(void* const* d_in, const int* in_sizes, int n_in,
                              void* d_out, int out_size, void* d_ws, size_t ws_size,
                              hipStream_t stream) {
  const float* x  = (const float*)d_in[0];
  const float* Wq = (const float*)d_in[1];
  const float* Wk = (const float*)d_in[2];
  const float* Wv = (const float*)d_in[3];
  const float* Wo = (const float*)d_in[4];
  const float* qw = (const float*)d_in[5];
  const float* kw = (const float*)d_in[6];
  float* out = (float*)d_out;

  unsigned short* p = (unsigned short*)d_ws;
  unsigned short* xbf   = p; p += (size_t)4096 * 2048;
  unsigned short* WTqkv = p; p += (size_t)3072 * 2048;
  unsigned short* WoT   = p; p += (size_t)2048 * 2048;
  unsigned short* qkv   = p; p += (size_t)4096 * 3072;
  unsigned short* qTb   = p; p += (size_t)2 * 16 * 2048 * 128;
  unsigned short* kTb   = p; p += (size_t)2 * 4 * 2048 * 128;
  unsigned short* vTb   = p; p += (size_t)2 * 4 * 2048 * 128;
  unsigned short* ao    = p; p += (size_t)4096 * 2048;

  cvt_f32_bf16<<<4096, 256, 0, stream>>>(x, xbf, 4096 * 2048);
  transpose_cvt4<<<2560, 256, 0, stream>>>(Wq, Wk, Wv, Wo, WTqkv, WoT);

  // qkv projection: 8-phase 256^2 (16 x 12 = 192 blocks, grid%8==0)
  gemm_nt_256<unsigned short><<<192, 512, 0, stream>>>(xbf, WTqkv, qkv, 4096, 3072, 2048);

  norm_rope<<<20480, 256, 0, stream>>>(qkv, qw, kw, qTb, kTb);
  v_transpose<<<512, 256, 0, stream>>>(qkv, vTb);

  flash_attn<<<512, 256, 0, stream>>>(qTb, kTb, vTb, ao);

  // output projection: now also 8-phase 256^2 (16 x 8 = 128 blocks, grid%8==0)
  gemm_nt_256<float><<<128, 512, 0, stream>>>(ao, WoT, out, 4096, 2048, 2048);
}

// Round 4
// 319.335 us; speedup vs baseline: 1.0467x; 1.0467x over previous
//
#include <hip/hip_runtime.h>
#include <stdint.h>

#define LOG2E 1.4426950408889634f

typedef __attribute__((ext_vector_type(8))) short short8;
typedef __attribute__((ext_vector_type(4))) float floatx4;
typedef unsigned int u32;

__device__ __forceinline__ float bf2f(unsigned short h) {
  union { unsigned int u; float f; } v; v.u = ((unsigned int)h) << 16; return v.f;
}
__device__ __forceinline__ unsigned short f2bf(float f) {
  union { float f; unsigned int u; } v; v.f = f;
  unsigned int r = v.u + 0x7FFFu + ((v.u >> 16) & 1u);
  return (unsigned short)(r >> 16);
}
__device__ __forceinline__ u32 fbits(float f) {
  union { float f; u32 u; } v; v.f = f; return v.u;
}
// async global->LDS, 16B per lane. dst must be wave-contiguous (base + lane*16).
__device__ __forceinline__ void async16(void* lds, const void* g) {
  __builtin_amdgcn_global_load_lds((const __attribute__((address_space(1))) u32*)g,
                                   (__attribute__((address_space(3))) u32*)lds, 16, 0, 0);
}

// ---------------------------------------------------------------------------
// fp32 -> bf16 elementwise convert (8 elems/thread, vectorized)
__global__ __launch_bounds__(256) void cvt_f32_bf16(const float* __restrict__ src,
                                                    unsigned short* __restrict__ dst, int n) {
  int i = (blockIdx.x * 256 + threadIdx.x) * 8;
  if (i >= n) return;
  float4 a = ((const float4*)(src + i))[0];
  float4 b = ((const float4*)(src + i))[1];
  union { uint4 v; unsigned short u[8]; } o;
  o.u[0] = f2bf(a.x); o.u[1] = f2bf(a.y); o.u[2] = f2bf(a.z); o.u[3] = f2bf(a.w);
  o.u[4] = f2bf(b.x); o.u[5] = f2bf(b.y); o.u[6] = f2bf(b.z); o.u[7] = f2bf(b.w);
  *(uint4*)(dst + i) = o.v;
}

// ---------------------------------------------------------------------------
// All 4 weight transposes (+fp32->bf16) in one launch. 64x64 tiles.
// blocks [0,1024): Wq->WTqkv ; [1024,1280): Wk ; [1280,1536): Wv ; [1536,2560): Wo->WoT
__global__ __launch_bounds__(256) void transpose_cvt4(const float* __restrict__ Wq,
                                                      const float* __restrict__ Wk,
                                                      const float* __restrict__ Wv,
                                                      const float* __restrict__ Wo,
                                                      unsigned short* __restrict__ WTqkv,
                                                      unsigned short* __restrict__ WoT) {
  const int R = 2048;
  int bid = blockIdx.x;
  const float* src; unsigned short* dst; int C;
  if (bid < 1024) { src = Wq; dst = WTqkv; C = 2048; }
  else if (bid < 1280) { src = Wk; dst = WTqkv + (size_t)2048 * 2048; C = 512; bid -= 1024; }
  else if (bid < 1536) { src = Wv; dst = WTqkv + (size_t)2048 * 2048 + (size_t)512 * 2048; C = 512; bid -= 1280; }
  else { src = Wo; dst = WoT; C = 2048; bid -= 1536; }

  __shared__ unsigned short tile[64][65];
  int tc = C >> 6;
  int br = bid / tc, bc = bid % tc;
  int r0 = br << 6, c0 = bc << 6;
  int i = threadIdx.x >> 2, cc = (threadIdx.x & 3) << 4;
  const float4* g = (const float4*)(src + (size_t)(r0 + i) * C + c0 + cc);
  float4 f0 = g[0], f1 = g[1], f2 = g[2], f3 = g[3];
  unsigned short u[16];
  u[0]=f2bf(f0.x); u[1]=f2bf(f0.y); u[2]=f2bf(f0.z); u[3]=f2bf(f0.w);
  u[4]=f2bf(f1.x); u[5]=f2bf(f1.y); u[6]=f2bf(f1.z); u[7]=f2bf(f1.w);
  u[8]=f2bf(f2.x); u[9]=f2bf(f2.y); u[10]=f2bf(f2.z); u[11]=f2bf(f2.w);
  u[12]=f2bf(f3.x); u[13]=f2bf(f3.y); u[14]=f2bf(f3.z); u[15]=f2bf(f3.w);
#pragma unroll
  for (int j = 0; j < 16; ++j) tile[i][cc + j] = u[j];
  __syncthreads();
  union { uint4 v[2]; unsigned short u[16]; } buf;
#pragma unroll
  for (int j = 0; j < 16; ++j) buf.u[j] = tile[cc + j][i];
  uint4* o = (uint4*)(dst + (size_t)(c0 + i) * R + r0 + cc);
  o[0] = buf.v[0]; o[1] = buf.v[1];
}

// ---------------------------------------------------------------------------
// 8-phase 256x256 NT GEMM, faithful m201 structure (plain HIP).
// (see R2 notes: beat the old 128^2 structure by ~10us on qkv)
// Requires M%256==0, N%256==0, K%128==0, grid%8==0.
template <typename OutT>
__global__ __launch_bounds__(512, 2) void gemm_nt_256(const unsigned short* __restrict__ A,
                                                      const unsigned short* __restrict__ BT,
                                                      OutT* __restrict__ C,
                                                      int M, int N, int K) {
  (void)M;
  __shared__ unsigned short As[2][256 * 64];
  __shared__ unsigned short Bs[2][256 * 64];
  const int nbn = N >> 8;
  const int nwg = gridDim.x;
  int wg = blockIdx.x;
  {  // XCD-aware swizzle (bijective: nwg % 8 == 0)
    int cpx = nwg >> 3;
    wg = (wg & 7) * cpx + (wg >> 3);
  }
  const int m0 = (wg / nbn) << 8;
  const int n0 = (wg % nbn) << 8;
  const int tid = threadIdx.x;
  const int lane = tid & 63, wave = tid >> 6;
  const int l15 = lane & 15, quad = lane >> 4;
  const int wr = wave >> 2, wc = wave & 3;   // 2 x 4 wave grid
  const int rA = wr * 128 + l15;             // + mf*16
  const int rB = wc * 64 + l15;              // + nf*16

  floatx4 acc[8][4];
#pragma unroll
  for (int i = 0; i < 8; ++i)
#pragma unroll
    for (int j = 0; j < 4; ++j) acc[i][j] = (floatx4){0.f, 0.f, 0.f, 0.f};

  const unsigned short* Ag = A + (size_t)m0 * K;
  const unsigned short* Bg = BT + (size_t)n0 * K;

  // Stage row-half h (rows h*128..h*128+127, full BK=64): 2 loads/thread.
  auto STAGE = [&](unsigned short* dst, const unsigned short* g, int h) {
#pragma unroll
    for (int j = 0; j < 2; ++j) {
      int idx = j * 512 + tid;              // [0,1024)
      int row = h * 128 + (idx >> 3);
      int cl = (idx & 7) ^ (row & 7);       // logical chunk for stored chunk idx&7
      async16(dst + (size_t)h * 8192 + (size_t)idx * 8, g + (size_t)row * K + cl * 8);
    }
  };
  auto RD = [&](const unsigned short* buf, int row, int ks) -> short8 {
    int sc = ((ks << 2) + quad) ^ (row & 7);
    return *(const short8*)(buf + row * 64 + sc * 8);
  };

#define BAR() __builtin_amdgcn_s_barrier()
#define WAITL0() asm volatile("s_waitcnt lgkmcnt(0)" ::: "memory")

  // prologue: A(0) h0,h1; B(0) h0,h1; A(1) h0,h1 = 12 loads/thread
  STAGE(As[0], Ag, 0); STAGE(As[0], Ag, 1);
  STAGE(Bs[0], Bg, 0); STAGE(Bs[0], Bg, 1);
  STAGE(As[1], Ag + 64, 0); STAGE(As[1], Ag + 64, 1);
  asm volatile("s_waitcnt vmcnt(4)" ::: "memory");   // tile0 landed; A(1) in flight
  BAR();

  const int NT = K >> 6;
  short8 a0[4][2], a1[4][2], b0[2][2], b1[2][2];
  for (int t = 0; t < NT; ++t) {
    const unsigned short* Ac = As[t & 1];
    const unsigned short* Bc = Bs[t & 1];
    unsigned short* Ast = As[t & 1];         // stage target: A(t+2)
    unsigned short* Bst = Bs[(t + 1) & 1];   // stage target: B(t+1)

    // ---- phase 1: read a0 (mf0-3) + b0 (nf0-1) [12]; stage B(t+1)h0
#pragma unroll
    for (int mf = 0; mf < 4; ++mf)
#pragma unroll
      for (int ks = 0; ks < 2; ++ks) a0[mf][ks] = RD(Ac, rA + mf * 16, ks);
#pragma unroll
    for (int nf = 0; nf < 2; ++nf)
#pragma unroll
      for (int ks = 0; ks < 2; ++ks) b0[nf][ks] = RD(Bc, rB + nf * 16, ks);
    if (t + 1 < NT) STAGE(Bst, Bg + (size_t)(t + 1) * 64, 0);
    asm volatile("s_waitcnt lgkmcnt(8)" ::: "memory");
    BAR(); WAITL0();
    __builtin_amdgcn_s_setprio(1);
#pragma unroll
    for (int mf = 0; mf < 4; ++mf)
#pragma unroll
      for (int nf = 0; nf < 2; ++nf)
#pragma unroll
        for (int ks = 0; ks < 2; ++ks)
          acc[mf][nf] = __builtin_amdgcn_mfma_f32_16x16x32_bf16(a0[mf][ks], b0[nf][ks], acc[mf][nf], 0, 0, 0);
    __builtin_amdgcn_s_setprio(0);
    BAR();

    // ---- phase 2: read a1 (mf4-7) [8]; stage B(t+1)h1
#pragma unroll
    for (int mf = 0; mf < 4; ++mf)
#pragma unroll
      for (int ks = 0; ks < 2; ++ks) a1[mf][ks] = RD(Ac, rA + 64 + mf * 16, ks);
    if (t + 1 < NT) STAGE(Bst, Bg + (size_t)(t + 1) * 64, 1);
    BAR(); WAITL0();
    __builtin_amdgcn_s_setprio(1);
#pragma unroll
    for (int mf = 0; mf < 4; ++mf)
#pragma unroll
      for (int nf = 0; nf < 2; ++nf)
#pragma unroll
        for (int ks = 0; ks < 2; ++ks)
          acc[4 + mf][nf] = __builtin_amdgcn_mfma_f32_16x16x32_bf16(a1[mf][ks], b0[nf][ks], acc[4 + mf][nf], 0, 0, 0);
    __builtin_amdgcn_s_setprio(0);
    BAR();

    // ---- phase 3: read b1 (nf2-3) [4]; stage A(t+2)h0 (A(t) dead after ph2)
#pragma unroll
    for (int nf = 0; nf < 2; ++nf)
#pragma unroll
      for (int ks = 0; ks < 2; ++ks) b1[nf][ks] = RD(Bc, rB + 32 + nf * 16, ks);
    if (t + 2 < NT) STAGE(Ast, Ag + (size_t)(t + 2) * 64, 0);
    BAR(); WAITL0();
    __builtin_amdgcn_s_setprio(1);
#pragma unroll
    for (int mf = 0; mf < 4; ++mf)
#pragma unroll
      for (int nf = 0; nf < 2; ++nf)
#pragma unroll
        for (int ks = 0; ks < 2; ++ks)
          acc[4 + mf][2 + nf] = __builtin_amdgcn_mfma_f32_16x16x32_bf16(a1[mf][ks], b1[nf][ks], acc[4 + mf][2 + nf], 0, 0, 0);
    __builtin_amdgcn_s_setprio(0);
    BAR();

    // ---- phase 4: no reads; stage A(t+2)h1; counted vmcnt(4) per tile
    if (t + 2 < NT) {
      STAGE(Ast, Ag + (size_t)(t + 2) * 64, 1);
      asm volatile("s_waitcnt vmcnt(4)" ::: "memory");  // tile t+1 fully landed
    } else {
      asm volatile("s_waitcnt vmcnt(0)" ::: "memory");  // tail drain
    }
    BAR();
    __builtin_amdgcn_s_setprio(1);
#pragma unroll
    for (int mf = 0; mf < 4; ++mf)
#pragma unroll
      for (int nf = 0; nf < 2; ++nf)
#pragma unroll
        for (int ks = 0; ks < 2; ++ks)
          acc[mf][2 + nf] = __builtin_amdgcn_mfma_f32_16x16x32_bf16(a0[mf][ks], b1[nf][ks], acc[mf][2 + nf], 0, 0, 0);
    __builtin_amdgcn_s_setprio(0);
    BAR();
  }
#undef BAR
#undef WAITL0

#pragma unroll
  for (int mf = 0; mf < 8; ++mf)
#pragma unroll
    for (int nf = 0; nf < 4; ++nf)
#pragma unroll
      for (int r = 0; r < 4; ++r) {
        int m = m0 + wr * 128 + mf * 16 + quad * 4 + r;
        int n = n0 + wc * 64 + nf * 16 + l15;
        float v = acc[mf][nf][r];
        if constexpr (sizeof(OutT) == 2)
          C[(size_t)m * N + n] = (OutT)f2bf(v);
        else
          C[(size_t)m * N + n] = (OutT)v;
      }
}

// ---------------------------------------------------------------------------
// 8-phase 128x256 NT GEMM (fp32 out). Same schedule as gemm_nt_256, retiled so
// M=4096,N=2048 gives grid = 32x8 = 256 = exactly 1 block/CU (R3 post-mortem:
// 256^2 tiles -> 128 blocks left half the chip idle and LOST ~11us vs the old
// structure; geometry beats per-CU schedule quality at this shape).
// 8 waves (2Mx4N), per-wave 64x64 (acc[4][4]). LDS 96KB: A [2][128*64],
// B [2][256*64]. B staged in 128-row halves (2 loads/thr), A in 64-row halves
// (1 load/thr). Deadness: all A(t) reads done by ph2 (a0@ph1,a1@ph2) -> in-
// place A restage ph3/ph4; B restaged to opposite buffer. vmcnt(2) = A(t+2)'s
// 2 outstanding loads. Requires M%128==0, N%256==0, K%128==0, grid%8==0.
__global__ __launch_bounds__(512, 2) void gemm_nt_128x256(const unsigned short* __restrict__ A,
                                                          const unsigned short* __restrict__ BT,
                                                          float* __restrict__ C,
                                                          int M, int N, int K) {
  (void)M;
  __shared__ unsigned short As[2][128 * 64];
  __shared__ unsigned short Bs[2][256 * 64];
  const int nbn = N >> 8;
  const int nwg = gridDim.x;
  int wg = blockIdx.x;
  {  // XCD-aware swizzle (bijective: nwg % 8 == 0)
    int cpx = nwg >> 3;
    wg = (wg & 7) * cpx + (wg >> 3);
  }
  const int m0 = (wg / nbn) << 7;
  const int n0 = (wg % nbn) << 8;
  const int tid = threadIdx.x;
  const int lane = tid & 63, wave = tid >> 6;
  const int l15 = lane & 15, quad = lane >> 4;
  const int wr = wave >> 2, wc = wave & 3;   // 2 x 4 wave grid
  const int rA = wr * 64 + l15;              // + mf*16, mf in [0,4)
  const int rB = wc * 64 + l15;              // + nf*16, nf in [0,4)

  floatx4 acc[4][4];
#pragma unroll
  for (int i = 0; i < 4; ++i)
#pragma unroll
    for (int j = 0; j < 4; ++j) acc[i][j] = (floatx4){0.f, 0.f, 0.f, 0.f};

  const unsigned short* Ag = A + (size_t)m0 * K;
  const unsigned short* Bg = BT + (size_t)n0 * K;

  // B-half: 128 rows x 64k (16KB), 2 loads/thread.
  auto STAGE_B = [&](unsigned short* dst, const unsigned short* g, int h) {
#pragma unroll
    for (int j = 0; j < 2; ++j) {
      int idx = j * 512 + tid;
      int row = h * 128 + (idx >> 3);
      int cl = (idx & 7) ^ (row & 7);
      async16(dst + (size_t)h * 8192 + (size_t)idx * 8, g + (size_t)row * K + cl * 8);
    }
  };
  // A-half: 64 rows x 64k (8KB), 1 load/thread.
  auto STAGE_A = [&](unsigned short* dst, const unsigned short* g, int h) {
    int idx = tid;
    int row = h * 64 + (idx >> 3);
    int cl = (idx & 7) ^ (row & 7);
    async16(dst + (size_t)h * 4096 + (size_t)idx * 8, g + (size_t)row * K + cl * 8);
  };
  auto RD = [&](const unsigned short* buf, int row, int ks) -> short8 {
    int sc = ((ks << 2) + quad) ^ (row & 7);
    return *(const short8*)(buf + row * 64 + sc * 8);
  };

#define BAR() __builtin_amdgcn_s_barrier()
#define WAITL0() asm volatile("s_waitcnt lgkmcnt(0)" ::: "memory")

  // prologue: A(0) h0,h1 [2]; B(0) h0,h1 [4]; A(1) h0,h1 [2] = 8 loads/thread
  STAGE_A(As[0], Ag, 0); STAGE_A(As[0], Ag, 1);
  STAGE_B(Bs[0], Bg, 0); STAGE_B(Bs[0], Bg, 1);
  STAGE_A(As[1], Ag + 64, 0); STAGE_A(As[1], Ag + 64, 1);
  asm volatile("s_waitcnt vmcnt(2)" ::: "memory");   // tile0 landed; A(1) in flight
  BAR();

  const int NT = K >> 6;
  short8 a0[2][2], a1[2][2], b0[2][2], b1[2][2];
  for (int t = 0; t < NT; ++t) {
    const unsigned short* Ac = As[t & 1];
    const unsigned short* Bc = Bs[t & 1];
    unsigned short* Ast = As[t & 1];         // stage target: A(t+2), in-place
    unsigned short* Bst = Bs[(t + 1) & 1];   // stage target: B(t+1)

    // ---- phase 1: read a0 (mf0-1) + b0 (nf0-1) [8]; stage B(t+1)h0
#pragma unroll
    for (int mf = 0; mf < 2; ++mf)
#pragma unroll
      for (int ks = 0; ks < 2; ++ks) a0[mf][ks] = RD(Ac, rA + mf * 16, ks);
#pragma unroll
    for (int nf = 0; nf < 2; ++nf)
#pragma unroll
      for (int ks = 0; ks < 2; ++ks) b0[nf][ks] = RD(Bc, rB + nf * 16, ks);
    if (t + 1 < NT) STAGE_B(Bst, Bg + (size_t)(t + 1) * 64, 0);
    asm volatile("s_waitcnt lgkmcnt(4)" ::: "memory");
    BAR(); WAITL0();
    __builtin_amdgcn_s_setprio(1);
#pragma unroll
    for (int mf = 0; mf < 2; ++mf)
#pragma unroll
      for (int nf = 0; nf < 2; ++nf)
#pragma unroll
        for (int ks = 0; ks < 2; ++ks)
          acc[mf][nf] = __builtin_amdgcn_mfma_f32_16x16x32_bf16(a0[mf][ks], b0[nf][ks], acc[mf][nf], 0, 0, 0);
    __builtin_amdgcn_s_setprio(0);
    BAR();

    // ---- phase 2: read a1 (mf2-3) [4]; stage B(t+1)h1
#pragma unroll
    for (int mf = 0; mf < 2; ++mf)
#pragma unroll
      for (int ks = 0; ks < 2; ++ks) a1[mf][ks] = RD(Ac, rA + 32 + mf * 16, ks);
    if (t + 1 < NT) STAGE_B(Bst, Bg + (size_t)(t + 1) * 64, 1);
    BAR(); WAITL0();
    __builtin_amdgcn_s_setprio(1);
#pragma unroll
    for (int mf = 0; mf < 2; ++mf)
#pragma unroll
      for (int nf = 0; nf < 2; ++nf)
#pragma unroll
        for (int ks = 0; ks < 2; ++ks)
          acc[2 + mf][nf] = __builtin_amdgcn_mfma_f32_16x16x32_bf16(a1[mf][ks], b0[nf][ks], acc[2 + mf][nf], 0, 0, 0);
    __builtin_amdgcn_s_setprio(0);
    BAR();

    // ---- phase 3: read b1 (nf2-3) [4]; stage A(t+2)h0 (A(t) dead after ph2)
#pragma unroll
    for (int nf = 0; nf < 2; ++nf)
#pragma unroll
      for (int ks = 0; ks < 2; ++ks) b1[nf][ks] = RD(Bc, rB + 32 + nf * 16, ks);
    if (t + 2 < NT) STAGE_A(Ast, Ag + (size_t)(t + 2) * 64, 0);
    BAR(); WAITL0();
    __builtin_amdgcn_s_setprio(1);
#pragma unroll
    for (int mf = 0; mf < 2; ++mf)
#pragma unroll
      for (int nf = 0; nf < 2; ++nf)
#pragma unroll
        for (int ks = 0; ks < 2; ++ks)
          acc[2 + mf][2 + nf] = __builtin_amdgcn_mfma_f32_16x16x32_bf16(a1[mf][ks], b1[nf][ks], acc[2 + mf][2 + nf], 0, 0, 0);
    __builtin_amdgcn_s_setprio(0);
    BAR();

    // ---- phase 4: no reads; stage A(t+2)h1; counted vmcnt(2) per tile
    if (t + 2 < NT) {
      STAGE_A(Ast, Ag + (size_t)(t + 2) * 64, 1);
      asm volatile("s_waitcnt vmcnt(2)" ::: "memory");  // tile t+1 fully landed
    } else {
      asm volatile("s_waitcnt vmcnt(0)" ::: "memory");  // tail drain
    }
    BAR();
    __builtin_amdgcn_s_setprio(1);
#pragma unroll
    for (int mf = 0; mf < 2; ++mf)
#pragma unroll
      for (int nf = 0; nf < 2; ++nf)
#pragma unroll
        for (int ks = 0; ks < 2; ++ks)
          acc[mf][2 + nf] = __builtin_amdgcn_mfma_f32_16x16x32_bf16(a0[mf][ks], b1[nf][ks], acc[mf][2 + nf], 0, 0, 0);
    __builtin_amdgcn_s_setprio(0);
    BAR();
  }
#undef BAR
#undef WAITL0

#pragma unroll
  for (int mf = 0; mf < 4; ++mf)
#pragma unroll
    for (int nf = 0; nf < 4; ++nf)
#pragma unroll
      for (int r = 0; r < 4; ++r) {
        int m = m0 + wr * 64 + mf * 16 + quad * 4 + r;
        int n = n0 + wc * 64 + nf * 16 + l15;
        C[(size_t)m * N + n] = acc[mf][nf][r];
      }
}

// ---------------------------------------------------------------------------
// RMS-norm + RoPE for q (heads 0..15) and k (kv 0..3).
// q gets 1/sqrt(128)*LOG2E folded in: flash then uses exp2(score) directly.
__global__ __launch_bounds__(256) void norm_rope(const unsigned short* __restrict__ qkv,
                                                 const float* __restrict__ qw,
                                                 const float* __restrict__ kw,
                                                 unsigned short* __restrict__ qT,
                                                 unsigned short* __restrict__ kT) {
  const int S = 2048;
  int wid = blockIdx.x * 4 + (threadIdx.x >> 6);
  int lane = threadIdx.x & 63;
  int slot = wid % 20;
  int bs = wid / 20;
  int s = bs & (S - 1), b = bs >> 11;
  const unsigned short* src;
  unsigned short* dst;
  const float* w;
  float scale;
  if (slot < 16) {
    src = qkv + (size_t)bs * 3072 + slot * 128;
    dst = qT + ((size_t)(b * 16 + slot) * S + s) * 128;
    w = qw; scale = 0.08838834764831845f * 1.4426950408889634f;  // 1/sqrt(128) * log2(e)
  } else {
    int kvi = slot - 16;
    src = qkv + (size_t)bs * 3072 + 2048 + kvi * 128;
    dst = kT + ((size_t)(b * 4 + kvi) * S + s) * 128;
    w = kw; scale = 1.0f;
  }
  float x1 = bf2f(src[lane]), x2 = bf2f(src[lane + 64]);
  float ss = x1 * x1 + x2 * x2;
#pragma unroll
  for (int m = 1; m < 64; m <<= 1) ss += __shfl_xor(ss, m, 64);
  float rms = rsqrtf(ss * (1.0f / 128.0f) + 1e-6f);
  float y1 = x1 * rms * w[lane];
  float y2 = x2 * rms * w[lane + 64];
  float ang = (float)s * exp2f((float)lane * -0.2076205059304601f);
  float c = cosf(ang), sn = sinf(ang);
  float o1 = (y1 * c - y2 * sn) * scale;
  float o2 = (y2 * c + y1 * sn) * scale;
  dst[lane] = f2bf(o1);
  dst[lane + 64] = f2bf(o2);
}

// ---------------------------------------------------------------------------
// V transpose: qkv v-slice (B,S,KV,128) bf16 -> vT (B,KV,128,S) bf16. 64x64 tiles.
__global__ __launch_bounds__(256) void v_transpose(const unsigned short* __restrict__ qkv,
                                                   unsigned short* __restrict__ vT) {
  const int S = 2048;
  int bid = blockIdx.x;
  int dt = bid & 1, st = (bid >> 1) & 31, kv = (bid >> 6) & 3, b = bid >> 8;
  int s0 = st << 6, d0 = dt << 6;
  __shared__ unsigned short tile[64][65];
  int i = threadIdx.x >> 2, cc = (threadIdx.x & 3) << 4;
  union { uint4 v[2]; unsigned short u[16]; } buf;
  const uint4* g = (const uint4*)(qkv + ((size_t)(b * S) + s0 + i) * 3072 + 2560 + kv * 128 + d0 + cc);
  buf.v[0] = g[0]; buf.v[1] = g[1];
#pragma unroll
  for (int j = 0; j < 16; ++j) tile[i][cc + j] = buf.u[j];
  __syncthreads();
#pragma unroll
  for (int j = 0; j < 16; ++j) buf.u[j] = tile[cc + j][i];
  uint4* o = (uint4*)(vT + ((size_t)(b * 4 + kv) * 128 + d0 + i) * S + s0 + cc);
  o[0] = buf.v[0]; o[1] = buf.v[1];
}

// ---------------------------------------------------------------------------
// MFMA flash attention v3, non-causal. Block = (b,h,128 q-rows), 4 waves x 32 rows.
// No-max softmax (scores bounded: |s|<=sqrt(128), LOG2E pre-folded into q).
// K/V double-buffered via global_load_lds prefetch; single barrier per kt.
// T5: setprio(1) around both MFMA clusters (m191 regime; R1 +4.6%).
// Byte-identical since R1 — noise band over 4 runs: 83.7-93.5 us.
__global__ __launch_bounds__(256, 2) void flash_attn(const unsigned short* __restrict__ qT,
                                                     const unsigned short* __restrict__ kT,
                                                     const unsigned short* __restrict__ vT,
                                                     unsigned short* __restrict__ ao) {
  const int S = 2048;
  int bid = blockIdx.x;
  int qt = bid & 15, h = (bid >> 4) & 15, b = bid >> 8;
  int kv = h >> 2;
  int tid = threadIdx.x;
  int lane = tid & 63, wave = tid >> 6;
  int l15 = lane & 15, quad = lane >> 4;

  __shared__ unsigned short Ks[2][64 * 128];   // keys x dh, 16 chunks/row, XOR swizzled
  __shared__ unsigned short VTs[2][128 * 64];  // d x keys, 8 chunks/row, XOR swizzled
  __shared__ unsigned short Ps[4][32 * 64];    // per-wave P in PV-A layout, swizzled
  unsigned short* Psw = Ps[wave];

  // Q fragments (B-operand of S^T: B[n=qrow][k=dh]), register-resident
  short8 bq[2][4];
  const unsigned short* qbase = qT + ((size_t)(b * 16 + h) * S + qt * 128 + wave * 32) * 128;
#pragma unroll
  for (int nt = 0; nt < 2; ++nt)
#pragma unroll
    for (int kk = 0; kk < 4; ++kk)
      bq[nt][kk] = *(const short8*)(qbase + (size_t)(nt * 16 + l15) * 128 + kk * 32 + quad * 8);

  floatx4 O[2][8];
#pragma unroll
  for (int mt = 0; mt < 2; ++mt)
#pragma unroll
    for (int dt = 0; dt < 8; ++dt) O[mt][dt] = (floatx4){0.f, 0.f, 0.f, 0.f};
  float l_acc[2] = {0.f, 0.f};

  const size_t kbase = (size_t)(b * 4 + kv) * S * 128;
  const size_t vbase = (size_t)(b * 4 + kv) * 128 * S;

  // prefetch tile 0 into buffer 0
#pragma unroll
  for (int i = 0; i < 4; ++i) {
    int Lc = (wave * 4 + i) * 64 + lane;
    int row = Lc >> 4, cjk = (lane & 15) ^ (row & 7);
    async16(Ks[0] + (size_t)Lc * 8, kT + kbase + (size_t)row * 128 + cjk * 8);
    int d = Lc >> 3, cjv = (lane & 7) ^ (d & 7);
    async16(VTs[0] + (size_t)Lc * 8, vT + vbase + (size_t)d * S + cjv * 8);
  }

  for (int kt = 0; kt < 32; ++kt) {
    int cur = kt & 1;
    __syncthreads();  // drains prefetch for tile kt; fences reads of buf cur^1 (kt-1)
    if (kt + 1 < 32) {
#pragma unroll
      for (int i = 0; i < 4; ++i) {
        int Lc = (wave * 4 + i) * 64 + lane;
        int row = Lc >> 4, cjk = (lane & 15) ^ (row & 7);
        async16(Ks[cur ^ 1] + (size_t)Lc * 8,
                kT + kbase + (size_t)((kt + 1) * 64 + row) * 128 + cjk * 8);
        int d = Lc >> 3, cjv = (lane & 7) ^ (d & 7);
        async16(VTs[cur ^ 1] + (size_t)Lc * 8,
                vT + vbase + (size_t)d * S + (kt + 1) * 64 + cjv * 8);
      }
    }

    // S^T = K * Q^T : C[m=key][n=qrow]
    floatx4 st[4][2];
#pragma unroll
    for (int a = 0; a < 4; ++a)
#pragma unroll
      for (int nt = 0; nt < 2; ++nt) st[a][nt] = (floatx4){0.f, 0.f, 0.f, 0.f};
    __builtin_amdgcn_s_setprio(1);
#pragma unroll
    for (int kk = 0; kk < 4; ++kk)
#pragma unroll
      for (int a = 0; a < 4; ++a) {
        int m = a * 16 + l15;
        short8 ak = *(const short8*)(&Ks[cur][(m * 16 + ((kk * 4 + quad) ^ (m & 7))) * 8]);
#pragma unroll
        for (int nt = 0; nt < 2; ++nt)
          st[a][nt] = __builtin_amdgcn_mfma_f32_16x16x32_bf16(ak, bq[nt][kk], st[a][nt], 0, 0, 0);
      }
    __builtin_amdgcn_s_setprio(0);

    // P = exp2(S^T); pack to bf16 into per-wave Ps (PV-A layout); l partials per lane.
#pragma unroll
    for (int nt = 0; nt < 2; ++nt) {
      int m = nt * 16 + l15;
#pragma unroll
      for (int a = 0; a < 4; ++a) {
        float e0 = __builtin_amdgcn_exp2f(st[a][nt][0]);
        float e1 = __builtin_amdgcn_exp2f(st[a][nt][1]);
        float e2 = __builtin_amdgcn_exp2f(st[a][nt][2]);
        float e3 = __builtin_amdgcn_exp2f(st[a][nt][3]);
        l_acc[nt] += (e0 + e1) + (e2 + e3);
        u32 p01 = __builtin_amdgcn_perm(fbits(e1) + 0x8000u, fbits(e0) + 0x8000u, 0x07060302u);
        u32 p23 = __builtin_amdgcn_perm(fbits(e3) + 0x8000u, fbits(e2) + 0x8000u, 0x07060302u);
        int c = (a * 2 + (quad >> 1)) ^ (m & 7);
        uint2 pk; pk.x = p01; pk.y = p23;
        *(uint2*)(&Psw[(m * 8 + c) * 8 + (quad & 1) * 4]) = pk;
      }
    }

    // PV: O[m=qrow][n=d] += P[m][key] * VT[n][key]
    __builtin_amdgcn_s_setprio(1);
#pragma unroll
    for (int kk2 = 0; kk2 < 2; ++kk2) {
      short8 ap[2];
#pragma unroll
      for (int mt = 0; mt < 2; ++mt) {
        int m = mt * 16 + l15;
        ap[mt] = *(const short8*)(&Psw[(m * 8 + ((kk2 * 4 + quad) ^ (m & 7))) * 8]);
      }
#pragma unroll
      for (int dt = 0; dt < 8; ++dt) {
        int n = dt * 16 + l15;
        short8 bv = *(const short8*)(&VTs[cur][(n * 8 + ((kk2 * 4 + quad) ^ (n & 7))) * 8]);
#pragma unroll
        for (int mt = 0; mt < 2; ++mt)
          O[mt][dt] = __builtin_amdgcn_mfma_f32_16x16x32_bf16(ap[mt], bv, O[mt][dt], 0, 0, 0);
      }
    }
    __builtin_amdgcn_s_setprio(0);
  }

  // epilogue: reduce l across quads, normalize, store
  float linv[2];
#pragma unroll
  for (int nt = 0; nt < 2; ++nt) {
    float l = l_acc[nt];
    l += __shfl_xor(l, 16, 64);
    l += __shfl_xor(l, 32, 64);
    linv[nt] = 1.f / l;
  }
#pragma unroll
  for (int mt = 0; mt < 2; ++mt)
#pragma unroll
    for (int r = 0; r < 4; ++r) {
      float inv = __shfl(linv[mt], quad * 4 + r, 64);
      int s = qt * 128 + wave * 32 + mt * 16 + quad * 4 + r;
#pragma unroll
      for (int dt = 0; dt < 8; ++dt) {
        int d = dt * 16 + l15;
        ao[((size_t)(b * S + s) * 16 + h) * 128 + d] = f2bf(O[mt][dt][r] * inv);
      }
    }
}

// ---------------------------------------------------------------------------
extern "C" void kernel_launch(void* const* d_in, const int* in_sizes, int n_in,
                              void* d_out, int out_size, void* d_ws, size_t ws_size,
                              hipStream_t stream) {
  const float* x  = (const float*)d_in[0];
  const float* Wq = (const float*)d_in[1];
  const float* Wk = (const float*)d_in[2];
  const float* Wv = (const float*)d_in[3];
  const float* Wo = (const float*)d_in[4];
  const float* qw = (const float*)d_in[5];
  const float* kw = (const float*)d_in[6];
  float* out = (float*)d_out;

  unsigned short* p = (unsigned short*)d_ws;
  unsigned short* xbf   = p; p += (size_t)4096 * 2048;
  unsigned short* WTqkv = p; p += (size_t)3072 * 2048;
  unsigned short* WoT   = p; p += (size_t)2048 * 2048;
  unsigned short* qkv   = p; p += (size_t)4096 * 3072;
  unsigned short* qTb   = p; p += (size_t)2 * 16 * 2048 * 128;
  unsigned short* kTb   = p; p += (size_t)2 * 4 * 2048 * 128;
  unsigned short* vTb   = p; p += (size_t)2 * 4 * 2048 * 128;
  unsigned short* ao    = p; p += (size_t)4096 * 2048;

  cvt_f32_bf16<<<4096, 256, 0, stream>>>(x, xbf, 4096 * 2048);
  transpose_cvt4<<<2560, 256, 0, stream>>>(Wq, Wk, Wv, Wo, WTqkv, WoT);

  // qkv projection: 8-phase 256^2 (16 x 12 = 192 blocks, grid%8==0)
  gemm_nt_256<unsigned short><<<192, 512, 0, stream>>>(xbf, WTqkv, qkv, 4096, 3072, 2048);

  norm_rope<<<20480, 256, 0, stream>>>(qkv, qw, kw, qTb, kTb);
  v_transpose<<<512, 256, 0, stream>>>(qkv, vTb);

  flash_attn<<<512, 256, 0, stream>>>(qTb, kTb, vTb, ao);

  // output projection: 8-phase 128x256 -> 32 x 8 = 256 blocks = 1 per CU
  gemm_nt_128x256<<<256, 512, 0, stream>>>(ao, WoT, out, 4096, 2048, 2048);
}